// Round 11
// baseline (126.717 us; speedup 1.0000x reference)
//
#include <hip/hip_runtime.h>

#define B 4
#define F 128    // M
#define E 3000   // K
#define T 6000   // N
#define BN 48    // t-columns per block
#define KSTEP 32
#define NKT 94   // ceil(E/32); k 3000..3007 zero-padded in afrag
#define NTT 125  // T / BN
#define RQW 96   // qwords per bit-row  (24 chunks * 4 comps)
#define RDW 192  // dwords per bit-row

typedef float f32x4 __attribute__((ext_vector_type(4)));
typedef short bf16x8 __attribute__((ext_vector_type(8)));

static __device__ __forceinline__ unsigned short f32_bf16(float x) {
    unsigned u = __float_as_uint(x);
    u += 0x7FFFu + ((u >> 16) & 1u);
    return (unsigned short)(u >> 16);
}

// ---------------------------------------------------------------------------
// Kernel 0: pack features into MFMA fragment order (bf16), zero-padded in k.
// Verified R7-R10: lane l of frag (b,kt,ft) holds row m=ft*16+(l&15),
// k = kt*32 + (l>>4)*8 + j.
// ---------------------------------------------------------------------------
__global__ __launch_bounds__(256) void build_afrag(const float* __restrict__ feat,
                                                   unsigned short* __restrict__ afrag) {
    const int gid = blockIdx.x * 256 + threadIdx.x;
    if (gid >= B * NKT * 8 * 64) return;
    const int lane = gid & 63;
    const int frag = gid >> 6;
    const int ft = frag & 7;
    const int kt = (frag >> 3) % NKT;
    const int b  = frag / (8 * NKT);
    const int m  = ft * 16 + (lane & 15);
    const int k0 = kt * 32 + (lane >> 4) * 8;
    const float* src = feat + ((size_t)b * F + m) * E;
    unsigned short v[8];
#pragma unroll
    for (int j = 0; j < 8; ++j) {
        const int k = k0 + j;
        v[j] = (k < E) ? f32_bf16(src[k]) : (unsigned short)0;
    }
    uint4 pack;
    pack.x = (unsigned)v[0] | ((unsigned)v[1] << 16);
    pack.y = (unsigned)v[2] | ((unsigned)v[3] << 16);
    pack.z = (unsigned)v[4] | ((unsigned)v[5] << 16);
    pack.w = (unsigned)v[6] | ((unsigned)v[7] << 16);
    *reinterpret_cast<uint4*>(afrag + (size_t)frag * 512 + lane * 8) = pack;
}

// ---------------------------------------------------------------------------
// Kernel 1: bitpack. Wave = one contiguous 24 KB row of U (fill-kernel read
// pattern). Per 1 KB wave-load: 4 ballots -> 4 qwords. Layout:
// bitmask[rid][ch][c] bit i  <->  U[rid][ch*256 + 4*i + c] != 0.
// ---------------------------------------------------------------------------
__global__ __launch_bounds__(256) void bitpack(const float* __restrict__ unroll,
                                               unsigned long long* __restrict__ bitmask) {
    const int rid  = blockIdx.x * 4 + (threadIdx.x >> 6);   // 0..11999 = b*E+e
    const int lane = threadIdx.x & 63;
    const float* row = unroll + (size_t)rid * T;
    unsigned long long* orow = bitmask + (size_t)rid * RQW;

#pragma unroll
    for (int ch = 0; ch < 24; ++ch) {
        float4 v = make_float4(0.0f, 0.0f, 0.0f, 0.0f);
        if (ch < 23 || lane < 28)   // chunk 23: only t 5888..5999 exist
            v = *reinterpret_cast<const float4*>(row + ch * 256 + lane * 4);
        const unsigned long long b0 = __ballot(v.x != 0.0f);
        const unsigned long long b1 = __ballot(v.y != 0.0f);
        const unsigned long long b2 = __ballot(v.z != 0.0f);
        const unsigned long long b3 = __ballot(v.w != 0.0f);
        if (lane == 0) {
            orow[ch * 4 + 0] = b0;
            orow[ch * 4 + 1] = b1;
            orow[ch * 4 + 2] = b2;
            orow[ch * 4 + 3] = b3;
        }
    }
}

// ---------------------------------------------------------------------------
// Kernel 2: bit-GEMM. R9/R10-verified wave-split-K MFMA structure, but the
// B-operand is assembled in-register from the bitmask (no LDS staging at
// all). Per lane, t is fixed -> chunk/comp/bit-position are compile-start
// constants; per step: 24 dword loads (L1/L2-resident, 1.5 KB working set
// per step), 8 afrag loads, 24 MFMAs. Barrier-free main loop.
// ---------------------------------------------------------------------------
__global__ __launch_bounds__(256, 2) void unpool_mfma_bits(
        const unsigned* __restrict__ bm,
        const unsigned short* __restrict__ afrag,
        const float* __restrict__ occ,
        float* __restrict__ out) {
    __shared__ f32x4 red[2][3][3][64];               // 18432 B

    // m204 bijective XCD-chunk swizzle: adjacent tb land on the same XCD.
    const int nwg  = NTT * B;                        // 500
    const int orig = blockIdx.x + gridDim.x * blockIdx.y;
    const int q_ = nwg / 8, r_ = nwg % 8;            // 62, 4
    const int xcd = orig & 7, lin = orig >> 3;
    const int newid = (xcd < r_ ? xcd * (q_ + 1) : r_ * (q_ + 1) + (xcd - r_) * q_) + lin;
    const int tb = newid % NTT;
    const int b  = newid / NTT;
    const int t0 = tb * BN;

    const int tid  = threadIdx.x;
    const int lane = tid & 63;
    const int w    = tid >> 6;    // wave id: owns K-slice
    const int lrow = lane & 15;
    const int g    = lane >> 4;

    const unsigned short* ab = afrag + (size_t)b * NKT * 8 * 512;
    const unsigned* bmb = bm + (size_t)b * E * RDW;

    // Per-nt bit addressing (t fixed per lane for the whole kernel):
    // dword off = chunk*8 + comp*2 + high-half, bit = (t>>2)&31.
    int C[3], sh[3];
#pragma unroll
    for (int nt = 0; nt < 3; ++nt) {
        const int t = t0 + nt * 16 + lrow;
        C[nt]  = (t >> 8) * 8 + (t & 3) * 2 + ((t >> 7) & 1);
        sh[nt] = (t >> 2) & 31;
    }

    // K-slice: waves 0,1 -> 24 steps; waves 2,3 -> 23. (24+24+23+23 = 94)
    const int s0 = w * 23 + (w < 2 ? w : 2);
    const int send = s0 + 23 + (w < 2 ? 1 : 0);

    f32x4 acc[8][3] = {};

    for (int s = s0; s < send; ++s) {
        // Bitmask loads first (longest dependent chain: load -> pack -> MFMA).
        unsigned q[3][8];
        const unsigned* rp = bmb + (size_t)(32 * s + 8 * g) * RDW;
#pragma unroll
        for (int nt = 0; nt < 3; ++nt)
#pragma unroll
            for (int j = 0; j < 8; ++j)
                q[nt][j] = rp[j * RDW + C[nt]];

        // A-fragments (L2/L3).
        bf16x8 afr[8];
        const unsigned short* ap = ab + (size_t)s * 8 * 512 + lane * 8;
#pragma unroll
        for (int ft = 0; ft < 8; ++ft)
            afr[ft] = *reinterpret_cast<const bf16x8*>(ap + ft * 512);

        // Assemble B-frags: dword m packs (e = 32s+8g+2m, +1) at this lane's t.
        bf16x8 bf[3];
#pragma unroll
        for (int nt = 0; nt < 3; ++nt) {
            union { uint4 u; bf16x8 v; } bu;
            unsigned d[4];
#pragma unroll
            for (int m = 0; m < 4; ++m) {
                const unsigned lo = (q[nt][2 * m]     >> sh[nt]) & 1u;
                const unsigned hi = (q[nt][2 * m + 1] >> sh[nt]) & 1u;
                d[m] = (lo ? 0x3F80u : 0u) | (hi ? 0x3F800000u : 0u);
            }
            bu.u.x = d[0]; bu.u.y = d[1]; bu.u.z = d[2]; bu.u.w = d[3];
            bf[nt] = bu.v;
        }

#pragma unroll
        for (int ft = 0; ft < 8; ++ft) {
            acc[ft][0] = __builtin_amdgcn_mfma_f32_16x16x32_bf16(afr[ft], bf[0], acc[ft][0], 0, 0, 0);
            acc[ft][1] = __builtin_amdgcn_mfma_f32_16x16x32_bf16(afr[ft], bf[1], acc[ft][1], 0, 0, 0);
            acc[ft][2] = __builtin_amdgcn_mfma_f32_16x16x32_bf16(afr[ft], bf[2], acc[ft][2], 0, 0, 0);
        }
    }

    // Epilogue: combine 4 per-wave partials (R9/R10-verified). 4 rounds x 2.
    float inv[3];
#pragma unroll
    for (int nt = 0; nt < 3; ++nt)
        inv[nt] = 1.0f / occ[b * T + t0 + nt * 16 + lrow];
    float* ob = out + (size_t)b * F * T;

#pragma unroll
    for (int p = 0; p < 4; ++p) {
        __syncthreads();
#pragma unroll
        for (int c = 0; c < 2; ++c) {
            const int ft = 2 * p + c;
            const int fw = 2 * c + (p & 1);     // finalizer wave for this chunk
            if (w != fw) {
                const int slot = (w - fw + 4) % 4 - 1;   // 0..2
#pragma unroll
                for (int nt = 0; nt < 3; ++nt)
                    red[c][slot][nt][lane] = acc[ft][nt];
            }
        }
        __syncthreads();
#pragma unroll
        for (int c = 0; c < 2; ++c) {
            const int ft = 2 * p + c;
            const int fw = 2 * c + (p & 1);
            if (w == fw) {
#pragma unroll
                for (int nt = 0; nt < 3; ++nt) {
                    f32x4 v = acc[ft][nt];
#pragma unroll
                    for (int sI = 0; sI < 3; ++sI) v += red[c][sI][nt][lane];
                    const int t = t0 + nt * 16 + lrow;
#pragma unroll
                    for (int rr = 0; rr < 4; ++rr) {
                        const int f = ft * 16 + g * 4 + rr;
                        __builtin_nontemporal_store(v[rr] * inv[nt], ob + (size_t)f * T + t);
                    }
                }
            }
        }
    }
}

// ---------------------------------------------------------------------------
// Dense fallback (only if workspace is too small — slow but exact).
// ---------------------------------------------------------------------------
__global__ void unpool_dense_fallback(const float* __restrict__ features,
                                      const float* __restrict__ unroll,
                                      const float* __restrict__ occ,
                                      float* __restrict__ out) {
    const int b = blockIdx.z;
    const int f = blockIdx.y;
    const int t = blockIdx.x * 64 + threadIdx.x;
    if (t >= T) return;
    const float* frow = features + ((size_t)b * F + f) * E;
    const float* ubp = unroll + (size_t)b * E * T;
    float acc = 0.0f;
    for (int e = 0; e < E; ++e) acc += frow[e] * ubp[(size_t)e * T + t];
    out[((size_t)b * F + f) * T + t] = acc / occ[b * T + t];
}

extern "C" void kernel_launch(void* const* d_in, const int* in_sizes, int n_in,
                              void* d_out, int out_size, void* d_ws, size_t ws_size,
                              hipStream_t stream) {
    const float* features = (const float*)d_in[0];   // (B,F,E) fp32
    const float* unroll   = (const float*)d_in[1];   // (B,E,T) fp32 (binary)
    const float* occ      = (const float*)d_in[2];   // (B,T)   fp32
    float* out = (float*)d_out;                      // (B,F,T) fp32

    const size_t afrag_bytes = (size_t)B * NKT * 8 * 512 * sizeof(unsigned short); // ~3.1 MB
    const size_t bm_bytes    = (size_t)B * E * RQW * sizeof(unsigned long long);   // ~9.2 MB
    // bit-GEMM reads up to 8 rows past the bitmask end (zero-padded K tail);
    // keep 8 KB of slack inside ws.
    if (ws_size < afrag_bytes + bm_bytes + 8192) {
        dim3 g((T + 63) / 64, F, B);
        unpool_dense_fallback<<<g, 64, 0, stream>>>(features, unroll, occ, out);
        return;
    }

    unsigned short* afrag = (unsigned short*)d_ws;
    unsigned long long* bitmask =
        (unsigned long long*)((char*)d_ws + afrag_bytes);

    const int nthr = B * NKT * 8 * 64;  // 192512
    build_afrag<<<(nthr + 255) / 256, 256, 0, stream>>>(features, afrag);

    // One wave per U row, contiguous reads: 12000 rows / 4 waves = 3000 blocks.
    bitpack<<<(B * E) / 4, 256, 0, stream>>>(unroll, bitmask);

    unpool_mfma_bits<<<dim3(NTT, B), 256, 0, stream>>>(
        (const unsigned*)bitmask, afrag, occ, out);
}

// Round 12
// 69.544 us; speedup vs baseline: 1.8221x; 1.8221x over previous
//
#include <hip/hip_runtime.h>

#define B 4
#define F 128
#define E 3000
#define T 6000
#define K 16       // max stored nonzeros per output column (Poisson(2): P(>=16) ~ 5e-10)
#define CAP 1024   // LDS match-buffer entries/block (mean ~16, huge headroom)

// ---------------------------------------------------------------------------
// Kernel A: feature transpose FT[b][e][f] = features[b][f][e] (6.1 MB),
// plus zeroing of counts (runs before scan; removes a memset node). R5-proven.
// ---------------------------------------------------------------------------
__global__ __launch_bounds__(256) void feat_transpose_kernel(
        const float* __restrict__ features, float* __restrict__ ft,
        int* __restrict__ counts) {
    __shared__ float tile[32][33];
    const int b  = blockIdx.z;
    const int e0 = blockIdx.x * 32;
    const int f0 = blockIdx.y * 32;
    const int tx = threadIdx.x;  // 0..31
    const int ty = threadIdx.y;  // 0..7

    {
        const int blk = (blockIdx.z * gridDim.y + blockIdx.y) * gridDim.x + blockIdx.x;
        const int gtid = blk * 256 + ty * 32 + tx;
        if (gtid < B * T) counts[gtid] = 0;
    }

    const float* fb = features + (size_t)b * F * E;
    float* ob = ft + (size_t)b * E * F;
#pragma unroll
    for (int j = 0; j < 4; ++j) {
        const int f = f0 + ty + 8 * j;
        const int e = e0 + tx;
        tile[ty + 8 * j][tx] = (e < E) ? fb[(size_t)f * E + e] : 0.0f;
    }
    __syncthreads();
#pragma unroll
    for (int j = 0; j < 4; ++j) {
        const int e = e0 + ty + 8 * j;
        const int f = f0 + tx;
        if (e < E) ob[(size_t)e * F + f] = tile[tx][ty + 8 * j];
    }
}

// ---------------------------------------------------------------------------
// Kernel B: scan — WAVE-PER-ROW CONTIGUOUS streaming (the R12 A/B change).
// Each wave linearly reads one 24 KB row of U (24 x 1KB wave-loads, 8-deep
// batches for ILP). Nonzeros (~4/row) appended to LDS (lgkmcnt; vmcnt queue
// stays deep), flushed once per block with global atomics. Block = 4 rows,
// all same b (E % 4 == 0).
// ---------------------------------------------------------------------------
__global__ __launch_bounds__(256) void unpool_scan_rows(
        const float* __restrict__ unroll,
        int* __restrict__ counts,
        int* __restrict__ idx) {
    __shared__ int ls_cnt;
    __shared__ int2 ls_buf[CAP];

    const int rid  = blockIdx.x * 4 + (threadIdx.x >> 6);   // 0..11999
    const int lane = threadIdx.x & 63;
    const int b = rid / E;
    const int e = rid % E;
    const float* row = unroll + (size_t)rid * T;

    if (threadIdx.x == 0) ls_cnt = 0;
    __syncthreads();

    int* cbase = counts + b * T;
    int* ibase = idx + (size_t)b * T * K;

#define ANY_NZ(v) ((__float_as_uint(v.x) | __float_as_uint(v.y) | \
                    __float_as_uint(v.z) | __float_as_uint(v.w)) != 0u)

#pragma unroll 1
    for (int c0 = 0; c0 < 24; c0 += 8) {
        float4 v[8];
        // Issue 8 x 1KB wave-loads back-to-back (8 outstanding per wave).
#pragma unroll
        for (int u = 0; u < 8; ++u) {
            const int t4 = (c0 + u) * 256 + lane * 4;
            v[u] = (t4 < T) ? *reinterpret_cast<const float4*>(row + t4)
                            : make_float4(0.0f, 0.0f, 0.0f, 0.0f);
        }
#pragma unroll
        for (int u = 0; u < 8; ++u) {
            const int t4 = (c0 + u) * 256 + lane * 4;
            if (__ballot(ANY_NZ(v[u]))) {
                if (v[u].x != 0.0f) { int s = atomicAdd(&ls_cnt, 1); if (s < CAP) ls_buf[s] = make_int2(t4 + 0, e); }
                if (v[u].y != 0.0f) { int s = atomicAdd(&ls_cnt, 1); if (s < CAP) ls_buf[s] = make_int2(t4 + 1, e); }
                if (v[u].z != 0.0f) { int s = atomicAdd(&ls_cnt, 1); if (s < CAP) ls_buf[s] = make_int2(t4 + 2, e); }
                if (v[u].w != 0.0f) { int s = atomicAdd(&ls_cnt, 1); if (s < CAP) ls_buf[s] = make_int2(t4 + 3, e); }
            }
        }
    }
#undef ANY_NZ

    __syncthreads();
    const int n = ls_cnt;
    if (n <= CAP) {
        for (int i = threadIdx.x; i < n; i += 256) {
            const int2 p = ls_buf[i];
            const int c = atomicAdd(&cbase[p.x], 1);
            if (c < K) ibase[(size_t)p.x * K + c] = p.y;
        }
    } else {
        // Statistically impossible overflow: nothing was flushed, redo this
        // block's 4 rows with direct atomics (exact, slow).
        for (int c0 = 0; c0 < 24; ++c0) {
            const int t4 = c0 * 256 + lane * 4;
            if (t4 >= T) continue;
            const float4 v = *reinterpret_cast<const float4*>(row + t4);
            if (v.x != 0.0f) { int c = atomicAdd(&cbase[t4 + 0], 1); if (c < K) ibase[(size_t)(t4 + 0) * K + c] = e; }
            if (v.y != 0.0f) { int c = atomicAdd(&cbase[t4 + 1], 1); if (c < K) ibase[(size_t)(t4 + 1) * K + c] = e; }
            if (v.z != 0.0f) { int c = atomicAdd(&cbase[t4 + 2], 1); if (c < K) ibase[(size_t)(t4 + 2) * K + c] = e; }
            if (v.w != 0.0f) { int c = atomicAdd(&cbase[t4 + 3], 1); if (c < K) ibase[(size_t)(t4 + 3) * K + c] = e; }
        }
    }
}

// ---------------------------------------------------------------------------
// Kernel C: gather (R5-proven). Thread owns one t-column and 8 f-values:
// out[b,f,t] = inv * sum_k FT[b, e_k, f..f+3]. 1536 blocks (6/CU). NT stores
// keep FT L2-resident (out is write-once).
// ---------------------------------------------------------------------------
__global__ __launch_bounds__(256) void unpool_gather_kernel(
        const float* __restrict__ ft,
        const float* __restrict__ occ,
        const float* __restrict__ unroll,
        const int* __restrict__ counts,
        const int* __restrict__ idx,
        float* __restrict__ out) {
    const int b  = blockIdx.z;
    const int t  = blockIdx.x * 256 + threadIdx.x;
    const int f0 = blockIdx.y * 8;
    if (t >= T) return;

    const int c = counts[b * T + t];
    const float inv = 1.0f / occ[b * T + t];
    const float* fb = ft + (size_t)b * E * F;
    float* ob = out + (size_t)b * F * T + t;

    if (c <= K) {
        int es[K];
        const int4* ip4 = reinterpret_cast<const int4*>(idx + ((size_t)b * T + t) * K);
#pragma unroll
        for (int q = 0; q < 4; ++q) {
            const int4 v = ip4[q];
            es[4 * q + 0] = v.x; es[4 * q + 1] = v.y;
            es[4 * q + 2] = v.z; es[4 * q + 3] = v.w;
        }
#pragma unroll
        for (int j = 0; j < 2; ++j) {
            const int f = f0 + 4 * j;
            float4 a = make_float4(0.f, 0.f, 0.f, 0.f);
#pragma unroll
            for (int k = 0; k < K; ++k) {
                if (k < c) {
                    const float4 v = *reinterpret_cast<const float4*>(fb + (size_t)es[k] * F + f);
                    a.x += v.x; a.y += v.y; a.z += v.z; a.w += v.w;
                }
            }
            __builtin_nontemporal_store(a.x * inv, ob + (size_t)(f + 0) * T);
            __builtin_nontemporal_store(a.y * inv, ob + (size_t)(f + 1) * T);
            __builtin_nontemporal_store(a.z * inv, ob + (size_t)(f + 2) * T);
            __builtin_nontemporal_store(a.w * inv, ob + (size_t)(f + 3) * T);
        }
    } else {
        // Rare overflow of K: exact rescan of this column.
        for (int j = 0; j < 2; ++j) {
            const int f = f0 + 4 * j;
            float4 a = make_float4(0.f, 0.f, 0.f, 0.f);
            for (int e = 0; e < E; ++e) {
                if (unroll[((size_t)b * E + e) * T + t] != 0.0f) {
                    const float4 v = *reinterpret_cast<const float4*>(fb + (size_t)e * F + f);
                    a.x += v.x; a.y += v.y; a.z += v.z; a.w += v.w;
                }
            }
            ob[(size_t)(f + 0) * T] = a.x * inv;
            ob[(size_t)(f + 1) * T] = a.y * inv;
            ob[(size_t)(f + 2) * T] = a.z * inv;
            ob[(size_t)(f + 3) * T] = a.w * inv;
        }
    }
}

// ---------------------------------------------------------------------------
// Dense fallback (only if workspace is too small — slow but exact).
// ---------------------------------------------------------------------------
__global__ void unpool_dense_fallback(const float* __restrict__ features,
                                      const float* __restrict__ unroll,
                                      const float* __restrict__ occ,
                                      float* __restrict__ out) {
    const int b = blockIdx.z;
    const int f = blockIdx.y;
    const int t = blockIdx.x * 64 + threadIdx.x;
    if (t >= T) return;
    const float* frow = features + ((size_t)b * F + f) * E;
    const float* ub = unroll + (size_t)b * E * T;
    float acc = 0.0f;
    for (int e = 0; e < E; ++e) acc += frow[e] * ub[(size_t)e * T + t];
    out[((size_t)b * F + f) * T + t] = acc / occ[b * T + t];
}

extern "C" void kernel_launch(void* const* d_in, const int* in_sizes, int n_in,
                              void* d_out, int out_size, void* d_ws, size_t ws_size,
                              hipStream_t stream) {
    const float* features = (const float*)d_in[0];   // (B,F,E) fp32
    const float* unroll   = (const float*)d_in[1];   // (B,E,T) fp32 (binary)
    const float* occ      = (const float*)d_in[2];   // (B,T)   fp32
    float* out = (float*)d_out;                      // (B,F,T) fp32

    const size_t counts_bytes = (size_t)B * T * sizeof(int);      // 96 KB
    const size_t idx_bytes    = (size_t)B * T * K * sizeof(int);  // 1.5 MB
    const size_t ft_bytes     = (size_t)B * E * F * sizeof(float);// 6.1 MB

    if (ws_size < counts_bytes + idx_bytes + ft_bytes) {
        dim3 g((T + 63) / 64, F, B);
        unpool_dense_fallback<<<g, 64, 0, stream>>>(features, unroll, occ, out);
        return;
    }

    int*   counts = (int*)d_ws;
    int*   idx    = counts + (size_t)B * T;
    float* ft     = (float*)(idx + (size_t)B * T * K);

    // A: transpose features -> FT, zero counts. (94, 4, 4) x 256
    dim3 gt((E + 31) / 32, F / 32, B);
    feat_transpose_kernel<<<gt, dim3(32, 8), 0, stream>>>(features, ft, counts);

    // B: scan — wave-per-row contiguous streaming. 12000 rows / 4 = 3000 blocks.
    unpool_scan_rows<<<(B * E) / 4, 256, 0, stream>>>(unroll, counts, idx);

    // C: gather (24, 16, 4) = 1536 blocks x 256
    dim3 g2((T + 255) / 256, F / 8, B);
    unpool_gather_kernel<<<g2, 256, 0, stream>>>(ft, occ, unroll, counts, idx, out);
}